// Round 6
// baseline (219.124 us; speedup 1.0000x reference)
//
#include <hip/hip_runtime.h>

// Problem constants (from reference: shape (32,1,512,512) fp32)
#define BATCH 32
#define H 512
#define W 512
#define N_TOT (BATCH * H * W)          // 8388608
#define ROWS_TOTAL (BATCH * H)         // 16384
#define NBLOCKS (ROWS_TOTAL / 4)       // 4096 blocks x 4 waves = 1 row/wave
#define WS_FLOATS NBLOCKS

// R6: TLP over ILP. R5 (18 loads up front, 72 data VGPRs, launch_bounds
// (256,4) -> 4 waves/SIMD) landed ~33 us: with only 4 resident waves the
// SIMD drains whenever they overlap in their load-wait windows (compute
// ~350cy/phase vs ~600cy loaded latency needs ~6+ waves). This version
// phases the work per image (sobel A -> sobel B -> l_loss + sobel F) so
// peak live state is one image's 6 float4 + 30-float windows + 8 maxima +
// 2 kept center rows ~= 55-61 floats -> VGPR <= 64 -> 8 waves/SIMD
// (m69: occupancy steps at 64/128/256), doubling latency-hiding TLP.
// Everything else kept from R5: wave = full 512-px row (8 px/lane), column
// halos via __shfl (lane edges == image edges == zero pad, NO halo loads),
// zero __syncthreads in the hot path, XCD-bijective block swizzle
// (4096%8==0), per-block partial + 1-block finish (no atomics).
// NOTE: harness dur_us includes ~83 us of 268 MB fillBufferAligned
// re-poison (which also flushes L3 every iteration -> inputs always cold).

template <bool USE_PARTIALS>
__global__ __launch_bounds__(256, 8)
void fusion_loss_kernel(const float* __restrict__ A,
                        const float* __restrict__ B,
                        const float* __restrict__ F,
                        const int* __restrict__ scheme_arr,
                        float* __restrict__ sink)   // partials[] or out scalar
{
    __shared__ float red[4];

    const int t    = threadIdx.x;
    const int lane = t & 63;
    const int ty   = t >> 6;

    // XCD-bijective swizzle: each XCD owns 512 consecutive logical blocks
    // (2048 contiguous rows) -> vertical halo re-reads are same-XCD L2 hits.
    const int bid = blockIdx.x;
    const int lb  = (bid & 7) * (NBLOCKS / 8) + (bid >> 3);

    const int gy  = (lb << 2) | ty;       // global row 0..16383 (1 row/wave)
    const int b   = gy >> 9;              // batch (block = 4 aligned rows,
    const int y   = gy & (H - 1);         //  never spans a batch boundary)
    const int scheme = scheme_arr[b];
    const int off = gy * W + (lane << 3); // 8 px per lane

    const float* pA = A + off;
    const float* pB = B + off;
    const float* pF = F + off;
    const bool vm = (y > 0);              // wave-uniform
    const bool vp = (y < H - 1);

    const float4 z4 = make_float4(0.f, 0.f, 0.f, 0.f);

    // rows: (m0,m1)=y-1, (c0,c1)=y, (p0,p1)=y+1 ; u0=cols x0..+3, u1=+4..+7
#define LD2(d0_, d1_, p_) do {                                              \
    d0_ = *reinterpret_cast<const float4*>(p_);                             \
    d1_ = *reinterpret_cast<const float4*>((p_) + 4);                       \
} while (0)
#define LDROW(d0_, d1_, p_, v_) do {                                        \
    if (v_) LD2(d0_, d1_, p_); else { d0_ = z4; d1_ = z4; }                 \
} while (0)

    // 10-wide window from a row's two float4s; halos via shfl (lane edges
    // are image edges -> zero pad, matching reference 'same' conv).
#define BUILDW(w_, r0_, r1_) do {                                           \
    float lN_ = __shfl_up((r1_).w, 1, 64);                                  \
    float rN_ = __shfl_down((r0_).x, 1, 64);                                \
    if (lane == 0)  lN_ = 0.f;                                              \
    if (lane == 63) rN_ = 0.f;                                              \
    w_[0] = lN_;                                                            \
    w_[1] = (r0_).x; w_[2] = (r0_).y; w_[3] = (r0_).z; w_[4] = (r0_).w;     \
    w_[5] = (r1_).x; w_[6] = (r1_).y; w_[7] = (r1_).z; w_[8] = (r1_).w;     \
    w_[9] = rN_;                                                            \
} while (0)

    // sobel for one image's 8 outputs; OP_ consumes (j, sob)
#define SOBEL(OP_) do {                                                     \
    float wt_[10], wc_[10], wq_[10];                                        \
    BUILDW(wt_, m0, m1);                                                    \
    BUILDW(wc_, c0, c1);                                                    \
    BUILDW(wq_, p0, p1);                                                    \
    _Pragma("unroll")                                                       \
    for (int j = 0; j < 8; ++j) {                                           \
        const float gx  = (wt_[j + 2] - wt_[j])                             \
                        + 2.f * (wc_[j + 2] - wc_[j])                       \
                        + (wq_[j + 2] - wq_[j]);                            \
        const float gyv = (wt_[j] + 2.f * wt_[j + 1] + wt_[j + 2])          \
                        - (wq_[j] + 2.f * wq_[j + 1] + wq_[j + 2]);         \
        const float sob = fabsf(gx) + fabsf(gyv);                           \
        OP_;                                                                \
    }                                                                       \
} while (0)

    float4 m0, m1, c0, c1, p0, p1;
    float4 aC0, aC1, bC0, bC1;            // kept center rows for l_loss
    float  sobM[8];
    float  acc = 0.f;

    // ---- phase A ----
    LDROW(m0, m1, pA - W, vm);
    LD2(c0, c1, pA);
    LDROW(p0, p1, pA + W, vp);
    aC0 = c0; aC1 = c1;
    SOBEL(sobM[j] = sob);

    // ---- phase B ----
    LDROW(m0, m1, pB - W, vm);
    LD2(c0, c1, pB);
    LDROW(p0, p1, pB + W, vp);
    bC0 = c0; bC1 = c1;
    SOBEL(sobM[j] = fmaxf(sobM[j], sob));

    // ---- phase F: loads, then l_loss (frees aC/bC before sobel F) ----
    LDROW(m0, m1, pF - W, vm);
    LD2(c0, c1, pF);
    LDROW(p0, p1, pF + W, vp);
    {
        const float av[8] = {aC0.x, aC0.y, aC0.z, aC0.w,
                             aC1.x, aC1.y, aC1.z, aC1.w};
        const float bv[8] = {bC0.x, bC0.y, bC0.z, bC0.w,
                             bC1.x, bC1.y, bC1.z, bC1.w};
        const float fv[8] = {c0.x, c0.y, c0.z, c0.w,
                             c1.x, c1.y, c1.z, c1.w};
#pragma unroll
        for (int j = 0; j < 8; ++j) {
            const float ab = (scheme == 0) ? 0.5f * (av[j] + bv[j])
                           : (scheme == 1) ? fmaxf(av[j], bv[j])
                           : 0.f;
            acc += fabsf(ab - fv[j]);
        }
    }
    SOBEL(acc += fabsf(sob - sobM[j]));

#undef LD2
#undef LDROW
#undef BUILDW
#undef SOBEL

    // ---- reduction: 64-lane shuffle, cross-wave via LDS, one plain store
    // per block to a distinct workspace slot (parallel drain, no atomics).
#pragma unroll
    for (int offp = 32; offp > 0; offp >>= 1)
        acc += __shfl_down(acc, offp, 64);
    if (lane == 0) red[ty] = acc;
    __syncthreads();
    if (t == 0) {
        const float s = red[0] + red[1] + red[2] + red[3];
        if (USE_PARTIALS)
            sink[bid] = s;
        else
            atomicAdd(sink, s * (1.0f / (float)N_TOT)); // fallback path
    }
}

// 1-block finish: sum NBLOCKS=4096 partials (256 threads x 4 float4),
// scale by 1/N, write the scalar. Kernel boundary on the stream guarantees
// visibility of kernel1's plain stores.
__global__ __launch_bounds__(256)
void fusion_finish(const float* __restrict__ partials, float* __restrict__ out)
{
    __shared__ float red[4];
    const int t    = threadIdx.x;
    const int lane = t & 63;
    const int ty   = t >> 6;

    float s = 0.f;
#pragma unroll
    for (int k = 0; k < 4; ++k) {
        const float4 p = reinterpret_cast<const float4*>(partials)[t + 256 * k];
        s += (p.x + p.y) + (p.z + p.w);
    }
#pragma unroll
    for (int off = 32; off > 0; off >>= 1)
        s += __shfl_down(s, off, 64);
    if (lane == 0) red[ty] = s;
    __syncthreads();
    if (t == 0)
        out[0] = (red[0] + red[1] + red[2] + red[3]) * (1.0f / (float)N_TOT);
}

extern "C" void kernel_launch(void* const* d_in, const int* in_sizes, int n_in,
                              void* d_out, int out_size, void* d_ws, size_t ws_size,
                              hipStream_t stream)
{
    const float* A = (const float*)d_in[0];
    const float* B = (const float*)d_in[1];
    const float* F = (const float*)d_in[2];
    const int* scheme = (const int*)d_in[3];
    float* out = (float*)d_out;

    if (d_ws != nullptr && ws_size >= WS_FLOATS * sizeof(float)) {
        float* partials = (float*)d_ws;   // 16 KB, 16B-aligned
        fusion_loss_kernel<true><<<dim3(NBLOCKS), dim3(256), 0, stream>>>(
            A, B, F, scheme, partials);
        fusion_finish<<<dim3(1), dim3(256), 0, stream>>>(partials, out);
    } else {
        // Fallback: atomic path (d_out poisoned -> zero it).
        hipMemsetAsync(out, 0, sizeof(float), stream);
        fusion_loss_kernel<false><<<dim3(NBLOCKS), dim3(256), 0, stream>>>(
            A, B, F, scheme, out);
    }
}

// Round 7
// 128.589 us; speedup vs baseline: 1.7041x; 1.7041x over previous
//
#include <hip/hip_runtime.h>

// Problem constants (from reference: shape (32,1,512,512) fp32)
#define BATCH 32
#define H 512
#define W 512
#define N_TOT (BATCH * H * W)          // 8388608
#define ROWS_TOTAL (BATCH * H)         // 16384
#define NBLOCKS (ROWS_TOTAL / 4)       // 4096 blocks x 4 waves = 1 row/wave
#define WS_FLOATS NBLOCKS

// R7: phased dataflow with register budget by DESIGN, not decree.
// R6's __launch_bounds__(256,8) made the compiler cap VGPR at 32 (toolchain
// rule learned: (256,4)->128 cap, (256,8)->32 cap; nonlinear, untrustable)
// -> 176 MB scratch spill, 125 us. R5 (all 18 loads up front, 72 VGPR of
// payload, 4 waves/SIMD) = ~33 us kernel, the best so far.
// This round: plain __launch_bounds__(256); phased per image
// (l_loss -> sobel A -> sobel B -> sobel F) with only B/F CENTER rows
// preloaded (16 carried floats vs R5's 72); separable sobel (col sums
// s=t+2c+q, diffs d=t-q) evaluated in two 4-wide halves to cut both VALU
// ops and window transients; sched_barrier(0) between phases stops the
// scheduler from hoisting all loads back to the top (which is what would
// reinflate VGPR to R5's 128 / 4 waves per SIMD).
// Kept from R5 (verified): wave = full 512-px row (8 px/lane), column halos
// via __shfl with lane-edge zero pad (= image edge), zero __syncthreads in
// the hot path, XCD-bijective block swizzle, per-block partial store +
// 1-block finish (no atomics). Harness dur_us includes ~83 us of 268 MB
// re-poison fills (which also flush L3 -> inputs cold every iteration).

template <bool USE_PARTIALS>
__global__ __launch_bounds__(256)
void fusion_loss_kernel(const float* __restrict__ A,
                        const float* __restrict__ B,
                        const float* __restrict__ F,
                        const int* __restrict__ scheme_arr,
                        float* __restrict__ sink)   // partials[] or out scalar
{
    __shared__ float red[4];

    const int t    = threadIdx.x;
    const int lane = t & 63;
    const int ty   = t >> 6;

    // XCD-bijective swizzle: each XCD owns 512 consecutive logical blocks
    // (2048 contiguous rows) -> vertical halo re-reads are same-XCD L2 hits.
    const int bid = blockIdx.x;
    const int lb  = (bid & 7) * (NBLOCKS / 8) + (bid >> 3);

    const int gy  = (lb << 2) | ty;       // global row 0..16383 (1 row/wave)
    const int b   = gy >> 9;              // batch (block = 4 aligned rows,
    const int y   = gy & (H - 1);         //  never spans a batch boundary)
    const int scheme = scheme_arr[b];
    const int off = gy * W + (lane << 3); // 8 px per lane

    const float* pA = A + off;
    const float* pB = B + off;
    const float* pF = F + off;
    const bool vm = (y > 0);              // wave-uniform
    const bool vp = (y < H - 1);

    const float4 z4 = make_float4(0.f, 0.f, 0.f, 0.f);

#define LD2(d0_, d1_, p_) do {                                              \
    d0_ = *reinterpret_cast<const float4*>(p_);                             \
    d1_ = *reinterpret_cast<const float4*>((p_) + 4);                       \
} while (0)
#define LDROW(d0_, d1_, p_, v_) do {                                        \
    if (v_) LD2(d0_, d1_, p_); else { d0_ = z4; d1_ = z4; }                 \
} while (0)

    // Separable sobel over one 6-col half-window (outputs jj = JB_..JB_+3):
    // s[j] = t+2c+q (x-smoothing column sum), d[j] = t-q (y-derivative);
    // gx = s[j+2]-s[j], gy = d[j]+2d[j+1]+d[j+2], sob = |gx|+|gy|.
#define SOBH(JB_, T0,T1,T2,T3,T4,T5, C0,C1,C2,C3,C4,C5,                     \
             Q0,Q1,Q2,Q3,Q4,Q5, ...) do {                                   \
    const float s_[6] = {(T0) + 2.f*(C0) + (Q0), (T1) + 2.f*(C1) + (Q1),    \
                         (T2) + 2.f*(C2) + (Q2), (T3) + 2.f*(C3) + (Q3),    \
                         (T4) + 2.f*(C4) + (Q4), (T5) + 2.f*(C5) + (Q5)};   \
    const float d_[6] = {(T0) - (Q0), (T1) - (Q1), (T2) - (Q2),             \
                         (T3) - (Q3), (T4) - (Q4), (T5) - (Q5)};            \
    _Pragma("unroll")                                                       \
    for (int j = 0; j < 4; ++j) {                                           \
        const int jj = (JB_) + j; (void)jj;                                 \
        const float gx  = s_[j + 2] - s_[j];                                \
        const float gyv = d_[j] + 2.f * d_[j + 1] + d_[j + 2];              \
        const float sob = fabsf(gx) + fabsf(gyv);                           \
        __VA_ARGS__;                                                        \
    }                                                                       \
} while (0)

    // Full-row sobel from rows (m0,m1)=y-1, (c0,c1)=y, (p0,p1)=y+1.
    // Column halos via shfl; lane edges are image edges -> zero pad.
#define SOBEL(...) do {                                                     \
    float lt_ = __shfl_up(m1.w, 1, 64),  rt_ = __shfl_down(m0.x, 1, 64);    \
    float lc_ = __shfl_up(c1.w, 1, 64),  rc_ = __shfl_down(c0.x, 1, 64);    \
    float lq_ = __shfl_up(p1.w, 1, 64),  rq_ = __shfl_down(p0.x, 1, 64);    \
    if (lane == 0)  { lt_ = 0.f; lc_ = 0.f; lq_ = 0.f; }                    \
    if (lane == 63) { rt_ = 0.f; rc_ = 0.f; rq_ = 0.f; }                    \
    SOBH(0, lt_, m0.x, m0.y, m0.z, m0.w, m1.x,                              \
            lc_, c0.x, c0.y, c0.z, c0.w, c1.x,                              \
            lq_, p0.x, p0.y, p0.z, p0.w, p1.x, __VA_ARGS__);                \
    SOBH(4, m0.w, m1.x, m1.y, m1.z, m1.w, rt_,                              \
            c0.w, c1.x, c1.y, c1.z, c1.w, rc_,                              \
            p0.w, p1.x, p1.y, p1.z, p1.w, rq_, __VA_ARGS__);                \
} while (0)

    float4 m0, m1, c0, c1, p0, p1;      // current image's 3 rows
    float4 bc0, bc1, fc0, fc1;          // preloaded B/F center rows
    float  sobM[8];
    float  acc = 0.f;

    // ---- preamble: A's 3 rows + B/F center rows (10 independent loads) ----
    LDROW(m0, m1, pA - W, vm);
    LD2(c0, c1, pA);
    LDROW(p0, p1, pA + W, vp);
    LD2(bc0, bc1, pB);
    LD2(fc0, fc1, pF);

    // ---- l_loss on this row's 8 px (A center = c0,c1) ----
    {
        const float av[8] = {c0.x, c0.y, c0.z, c0.w, c1.x, c1.y, c1.z, c1.w};
        const float bv[8] = {bc0.x, bc0.y, bc0.z, bc0.w,
                             bc1.x, bc1.y, bc1.z, bc1.w};
        const float fv[8] = {fc0.x, fc0.y, fc0.z, fc0.w,
                             fc1.x, fc1.y, fc1.z, fc1.w};
#pragma unroll
        for (int j = 0; j < 8; ++j) {
            const float ab = (scheme == 0) ? 0.5f * (av[j] + bv[j])
                           : (scheme == 1) ? fmaxf(av[j], bv[j])
                           : 0.f;
            acc += fabsf(ab - fv[j]);
        }
    }

    // ---- phase A: sobel ----
    SOBEL(sobM[jj] = sob);
    __builtin_amdgcn_sched_barrier(0);

    // ---- phase B: m/p rows load here; center = preloaded bc ----
    LDROW(m0, m1, pB - W, vm);
    c0 = bc0; c1 = bc1;                 // register rename, free
    LDROW(p0, p1, pB + W, vp);
    SOBEL(sobM[jj] = fmaxf(sobM[jj], sob));
    __builtin_amdgcn_sched_barrier(0);

    // ---- phase F ----
    LDROW(m0, m1, pF - W, vm);
    c0 = fc0; c1 = fc1;
    LDROW(p0, p1, pF + W, vp);
    SOBEL(acc += fabsf(sob - sobM[jj]));

#undef LD2
#undef LDROW
#undef SOBH
#undef SOBEL

    // ---- reduction: 64-lane shuffle, cross-wave via LDS, one plain store
    // per block to a distinct workspace slot (parallel drain, no atomics).
#pragma unroll
    for (int offp = 32; offp > 0; offp >>= 1)
        acc += __shfl_down(acc, offp, 64);
    if (lane == 0) red[ty] = acc;
    __syncthreads();
    if (t == 0) {
        const float s = red[0] + red[1] + red[2] + red[3];
        if (USE_PARTIALS)
            sink[bid] = s;
        else
            atomicAdd(sink, s * (1.0f / (float)N_TOT)); // fallback path
    }
}

// 1-block finish: sum NBLOCKS=4096 partials (256 threads x 4 float4),
// scale by 1/N, write the scalar. Kernel boundary on the stream guarantees
// visibility of kernel1's plain stores.
__global__ __launch_bounds__(256)
void fusion_finish(const float* __restrict__ partials, float* __restrict__ out)
{
    __shared__ float red[4];
    const int t    = threadIdx.x;
    const int lane = t & 63;
    const int ty   = t >> 6;

    float s = 0.f;
#pragma unroll
    for (int k = 0; k < 4; ++k) {
        const float4 p = reinterpret_cast<const float4*>(partials)[t + 256 * k];
        s += (p.x + p.y) + (p.z + p.w);
    }
#pragma unroll
    for (int off = 32; off > 0; off >>= 1)
        s += __shfl_down(s, off, 64);
    if (lane == 0) red[ty] = s;
    __syncthreads();
    if (t == 0)
        out[0] = (red[0] + red[1] + red[2] + red[3]) * (1.0f / (float)N_TOT);
}

extern "C" void kernel_launch(void* const* d_in, const int* in_sizes, int n_in,
                              void* d_out, int out_size, void* d_ws, size_t ws_size,
                              hipStream_t stream)
{
    const float* A = (const float*)d_in[0];
    const float* B = (const float*)d_in[1];
    const float* F = (const float*)d_in[2];
    const int* scheme = (const int*)d_in[3];
    float* out = (float*)d_out;

    if (d_ws != nullptr && ws_size >= WS_FLOATS * sizeof(float)) {
        float* partials = (float*)d_ws;   // 16 KB, 16B-aligned
        fusion_loss_kernel<true><<<dim3(NBLOCKS), dim3(256), 0, stream>>>(
            A, B, F, scheme, partials);
        fusion_finish<<<dim3(1), dim3(256), 0, stream>>>(partials, out);
    } else {
        // Fallback: atomic path (d_out poisoned -> zero it).
        hipMemsetAsync(out, 0, sizeof(float), stream);
        fusion_loss_kernel<false><<<dim3(NBLOCKS), dim3(256), 0, stream>>>(
            A, B, F, scheme, out);
    }
}